// Round 14
// baseline (50.760 us; speedup 1.0000x reference)
//
#include <hip/hip_runtime.h>
#include <hip/hip_bf16.h>

// Problem constants
#define B_ 2
#define C_ 256
#define O_ 256
#define T_ 16
#define H_ 64
#define W_ 64

typedef __bf16 bf16x8 __attribute__((ext_vector_type(8)));
typedef float  f32x4  __attribute__((ext_vector_type(4)));

// ws layout:
//   [0, 131072)       : W3d bf16 LINEAR image [256 o][256 c] (512 B rows)
//   [131072, 163840)  : obj f32 [b][t][o]
#define WS_OBJ_OFF 131072

// LDS-only barrier (r13): orders ds ops across waves without draining the
// vmem store queue.
__device__ __forceinline__ void barrier_lds_only() {
    asm volatile("s_waitcnt lgkmcnt(0)" ::: "memory");
    __builtin_amdgcn_s_barrier();
    asm volatile("" ::: "memory");
}

// ---------------- prep kernel (identical to r9/r12/r13) ----------------
__global__ __launch_bounds__(256) void prep_kernel(
    const float* __restrict__ fea_obj, const float* __restrict__ W3d,
    const float* __restrict__ W1d, const float* __restrict__ b1d,
    __bf16* __restrict__ wsW, float* __restrict__ wsObj) {
    const int bid = blockIdx.x;
    const int tid = threadIdx.x;
    if (bid < 32) {
        const int b = bid >> 4, t = bid & 15;
        __shared__ float fo[C_];
        fo[tid] = fea_obj[(b * C_ + tid) * T_ + t];
        __syncthreads();
        const int o = tid;
        const float4* wrow = (const float4*)(W1d + o * C_);
        float s = 0.f;
#pragma unroll 8
        for (int cq = 0; cq < C_ / 4; ++cq) {
            float4 wv = wrow[cq];
            s += wv.x * fo[cq * 4 + 0] + wv.y * fo[cq * 4 + 1] +
                 wv.z * fo[cq * 4 + 2] + wv.w * fo[cq * 4 + 3];
        }
        wsObj[(b * T_ + t) * O_ + o] = s + b1d[o];
    } else {
        const int g = (bid - 32) * 256 + tid;
        const int o = g >> 5;
        const int cg = g & 31;
        const float* sp = W3d + o * C_ + cg * 8;
        float4 a0 = *(const float4*)sp;
        float4 a1 = *(const float4*)(sp + 4);
        bf16x8 pk;
        pk[0] = (__bf16)a0.x; pk[1] = (__bf16)a0.y;
        pk[2] = (__bf16)a0.z; pk[3] = (__bf16)a0.w;
        pk[4] = (__bf16)a1.x; pk[5] = (__bf16)a1.y;
        pk[6] = (__bf16)a1.z; pk[7] = (__bf16)a1.w;
        *(bf16x8*)((char*)wsW + o * 512 + cg * 16) = pk;
    }
}

// ---------------- main kernel (r13 + operand swap -> float4 stores) --------
// Grid 512 = wb(2) x hg(8) x bt(32). Block: 512 thr = 8 waves.
// Wave tile 32o x 32w; A (W3d bf16) regs af[2][8]; B panel [cg][w][16B].
// r14 change: acc = mfma(Zfrag, Wfrag, acc) -> D[w][o]: reg index r = 4
// CONSECUTIVE w -> epilogue stores one float4 per quad (4 x 1KB store
// instructions per wave-h instead of 16 x 256B). A/B fragments share the
// same per-lane layout on this shape, so the swap needs no repacking.
__global__ __attribute__((amdgpu_flat_work_group_size(512, 512)))
void main_kernel(
    const float* __restrict__ fea_th, const float* __restrict__ fea_tw,
    const float* __restrict__ heatmap, const float* __restrict__ mask,
    const float* __restrict__ b3d,
    const __bf16* __restrict__ wsW, const float* __restrict__ wsObj,
    float* __restrict__ out) {
    __shared__ __align__(16) char smem[75776];
    // panels: P0=0, P1=16384, P2=32768, P3=49152 (each [32 cg][32 w][16B])
    float* sTh  = (float*)(smem + 65536);    // [8 h][256 c] f32
    float* sPb  = (float*)(smem + 73728);    // [256] b3d
    float* sObj = (float*)(smem + 74752);    // [256] obj for this (b,t)

    const int tid  = threadIdx.x;
    const int lane = tid & 63;
    const int wv   = tid >> 6;       // 0..7 -> o base wv*32
    const int kgrp = lane >> 4;
    const int l15  = lane & 15;

    const int bid = blockIdx.x;
    const int wb = bid & 1, hg = (bid >> 1) & 7, bt = bid >> 4;
    const int b = bt >> 4, t = bt & 15;
    const int h0 = hg * 8, w0 = wb * 32;

    // ---- stage th / pb / obj (first 256 threads) ----
    const float* objp = wsObj + (b * T_ + t) * O_;
    if (tid < 256) {
        const float* thp = fea_th + ((b * C_ + tid) * T_ + t) * H_ + h0;
        float4 v0 = *(const float4*)thp;
        float4 v1 = *(const float4*)(thp + 4);
        sTh[0 * 256 + tid] = v0.x;  sTh[1 * 256 + tid] = v0.y;
        sTh[2 * 256 + tid] = v0.z;  sTh[3 * 256 + tid] = v0.w;
        sTh[4 * 256 + tid] = v1.x;  sTh[5 * 256 + tid] = v1.y;
        sTh[6 * 256 + tid] = v1.z;  sTh[7 * 256 + tid] = v1.w;
        sPb[tid]  = b3d[tid];
        sObj[tid] = objp[tid];
    }

    // ---- tw -> per-thread bf16 slice (w = w0 + (tid&31), c in [cs, cs+16)) ----
    const int wl = tid & 31;
    const int cs = (tid >> 5) * 16;
    bf16x8 twb0, twb1;
    {
        const float* twp = fea_tw + ((b * C_ + cs) * T_ + t) * W_ + w0 + wl;
#pragma unroll
        for (int j = 0; j < 8; ++j) twb0[j] = (__bf16)twp[j * (T_ * W_)];
#pragma unroll
        for (int j = 0; j < 8; ++j) twb1[j] = (__bf16)twp[(8 + j) * (T_ * W_)];
    }

    // ---- A panel -> registers: af[mf][ks], 64 VGPR ----
    bf16x8 af[2][8];
#pragma unroll
    for (int mf = 0; mf < 2; ++mf)
#pragma unroll
        for (int ks = 0; ks < 8; ++ks)
            af[mf][ks] = *(const bf16x8*)(
                wsW + (wv * 32 + mf * 16 + l15) * 256 + ks * 32 + kgrp * 8);

    // build: thread (wl, cs) -> cg0 = cs/8, conflict-free contiguous writes
    const int wbyte = wl * 16;
    const int cg0   = (tid >> 5) * 2;

    auto build = [&](int hl, char* dst) {
        const float* thp = sTh + hl * 256 + cs;
        const f32x4 t0 = *(const f32x4*)thp;
        const f32x4 t1 = *(const f32x4*)(thp + 4);
        const f32x4 t2 = *(const f32x4*)(thp + 8);
        const f32x4 t3 = *(const f32x4*)(thp + 12);
        bf16x8 z0, z1;
        z0[0] = (__bf16)((float)twb0[0] * t0[0]);
        z0[1] = (__bf16)((float)twb0[1] * t0[1]);
        z0[2] = (__bf16)((float)twb0[2] * t0[2]);
        z0[3] = (__bf16)((float)twb0[3] * t0[3]);
        z0[4] = (__bf16)((float)twb0[4] * t1[0]);
        z0[5] = (__bf16)((float)twb0[5] * t1[1]);
        z0[6] = (__bf16)((float)twb0[6] * t1[2]);
        z0[7] = (__bf16)((float)twb0[7] * t1[3]);
        z1[0] = (__bf16)((float)twb1[0] * t2[0]);
        z1[1] = (__bf16)((float)twb1[1] * t2[1]);
        z1[2] = (__bf16)((float)twb1[2] * t2[2]);
        z1[3] = (__bf16)((float)twb1[3] * t2[3]);
        z1[4] = (__bf16)((float)twb1[4] * t3[0]);
        z1[5] = (__bf16)((float)twb1[5] * t3[1]);
        z1[6] = (__bf16)((float)twb1[6] * t3[2]);
        z1[7] = (__bf16)((float)twb1[7] * t3[3]);
        *(bf16x8*)(dst + cg0 * 512 + wbyte)       = z0;
        *(bf16x8*)(dst + (cg0 + 1) * 512 + wbyte) = z1;
    };

    __syncthreads();          // sTh / sPb / sObj ready
    build(0, smem);
    build(1, smem + 16384);
    __syncthreads();          // pair 0 ready

    const int hmb = (b * T_ + t) * (H_ * W_);
    const int rb  = kgrp * 512 + l15 * 16;   // read base within a panel

    // epilogue helper: D[w][o] layout -> float4 store along w
    auto epilogue = [&](f32x4 (&ac)[2][2], int hglb) {
#pragma unroll
        for (int nw = 0; nw < 2; ++nw) {
            const int wcol = w0 + nw * 16 + kgrp * 4;
            const f32x4 ht4 = *(const f32x4*)(heatmap + hmb + hglb * W_ + wcol);
            const f32x4 mk4 = *(const f32x4*)(mask    + hmb + hglb * W_ + wcol);
#pragma unroll
            for (int mo = 0; mo < 2; ++mo) {
                const int o = wv * 32 + mo * 16 + l15;
                const float pb = sPb[o];
                const float po = sObj[o];
                f32x4 v;
#pragma unroll
                for (int r = 0; r < 4; ++r) {
                    float x = ac[nw][mo][r] + pb;
                    x = x * (1.f - ht4[r]) + po * ht4[r];
                    v[r] = x * mk4[r];
                }
                *(f32x4*)(out + (((size_t)(b * O_ + o) * T_ + t) * H_ + hglb) * W_ + wcol) = v;
            }
        }
    };

    for (int p = 0; p < 4; ++p) {
        char* curA = smem + ((p & 1) ? 32768 : 0);
        char* curB = curA + 16384;
        char* nxtA = smem + ((p & 1) ? 0 : 32768);
        char* nxtB = nxtA + 16384;
        const int hA = h0 + 2 * p, hB = hA + 1;

        // ---- h = hA: MFMA from curA (operands swapped: D[w][o]) ----
        f32x4 acc[2][2] = {};
#pragma unroll
        for (int ks = 0; ks < 8; ++ks) {
            const bf16x8 b0 = *(const bf16x8*)(curA + rb + ks * 2048);
            const bf16x8 b1 = *(const bf16x8*)(curA + rb + ks * 2048 + 256);
            acc[0][0] = __builtin_amdgcn_mfma_f32_16x16x32_bf16(b0, af[0][ks], acc[0][0], 0, 0, 0);
            acc[0][1] = __builtin_amdgcn_mfma_f32_16x16x32_bf16(b0, af[1][ks], acc[0][1], 0, 0, 0);
            acc[1][0] = __builtin_amdgcn_mfma_f32_16x16x32_bf16(b1, af[0][ks], acc[1][0], 0, 0, 0);
            acc[1][1] = __builtin_amdgcn_mfma_f32_16x16x32_bf16(b1, af[1][ks], acc[1][1], 0, 0, 0);
        }
        if (p < 3) build(2 * p + 2, nxtA);
        epilogue(acc, hA);

        // ---- h = hB: MFMA from curB ----
        f32x4 acd[2][2] = {};
#pragma unroll
        for (int ks = 0; ks < 8; ++ks) {
            const bf16x8 b0 = *(const bf16x8*)(curB + rb + ks * 2048);
            const bf16x8 b1 = *(const bf16x8*)(curB + rb + ks * 2048 + 256);
            acd[0][0] = __builtin_amdgcn_mfma_f32_16x16x32_bf16(b0, af[0][ks], acd[0][0], 0, 0, 0);
            acd[0][1] = __builtin_amdgcn_mfma_f32_16x16x32_bf16(b0, af[1][ks], acd[0][1], 0, 0, 0);
            acd[1][0] = __builtin_amdgcn_mfma_f32_16x16x32_bf16(b1, af[0][ks], acd[1][0], 0, 0, 0);
            acd[1][1] = __builtin_amdgcn_mfma_f32_16x16x32_bf16(b1, af[1][ks], acd[1][1], 0, 0, 0);
        }
        if (p < 3) build(2 * p + 3, nxtB);
        epilogue(acd, hB);

        if (p < 3) barrier_lds_only();   // LDS-only: stores keep flowing
    }
}

extern "C" void kernel_launch(void* const* d_in, const int* in_sizes, int n_in,
                              void* d_out, int out_size, void* d_ws, size_t ws_size,
                              hipStream_t stream) {
    const float* fea_th  = (const float*)d_in[0];
    const float* fea_tw  = (const float*)d_in[1];
    const float* fea_obj = (const float*)d_in[2];
    const float* heatmap = (const float*)d_in[3];
    const float* mask    = (const float*)d_in[4];
    const float* W3d     = (const float*)d_in[5];
    const float* b3d     = (const float*)d_in[6];
    const float* W1d     = (const float*)d_in[7];
    const float* b1d     = (const float*)d_in[8];
    float* out = (float*)d_out;

    __bf16* wsW  = (__bf16*)d_ws;
    float* wsObj = (float*)((char*)d_ws + WS_OBJ_OFF);

    hipLaunchKernelGGL(prep_kernel, dim3(64), dim3(256), 0, stream,
                       fea_obj, W3d, W1d, b1d, wsW, wsObj);
    hipLaunchKernelGGL(main_kernel, dim3(512), dim3(512), 0, stream,
                       fea_th, fea_tw, heatmap, mask, b3d, wsW, wsObj, out);
}